// Round 9
// baseline (319.719 us; speedup 1.0000x reference)
//
#include <hip/hip_runtime.h>
#include <stdint.h>

#define HID 256
#define NMAXPIX (1025 * 1025)
#define NREP 4      // histogram replicas, replica-major
#define MBLK 512    // mega grid (co-resident: 2 blocks/CU x 256 CU)
#define NSEG (MBLK * 4)
#define SELMAX 2112
#define FLAG31 0x80000000u

// per-stage small-buffer layout (u32 units)
#define HA_OFF    0        // 4 x 2048
#define HB_OFF    8192     // 4 x 2048
#define HC_OFF    16384    // 4 x 1024
#define SLOT1_OFF 20480    // u64 (pfx2, rem2|flag)
#define SLOT2_OFF 20482    // u64 (K, t|flag)
#define CTR1_OFF  20484
#define CTR2_OFF  20485
#define BLKT_OFF  20544    // 512 lookback slots
#define STAGE_U32 21120

#define ALOAD32(p)  __hip_atomic_load((p), __ATOMIC_RELAXED, __HIP_MEMORY_SCOPE_AGENT)
#define ALOAD64(p)  __hip_atomic_load((p), __ATOMIC_RELAXED, __HIP_MEMORY_SCOPE_AGENT)
#define ASTORE32(p, v) __hip_atomic_store((p), (v), __ATOMIC_RELAXED, __HIP_MEMORY_SCOPE_AGENT)
#define ASTORE64(p, v) __hip_atomic_store((p), (v), __ATOMIC_RELAXED, __HIP_MEMORY_SCOPE_AGENT)

// ---------------- MLP eval (single point), float4 LDS weight reads ----------------
__device__ __forceinline__ float mlp_eval4(float wx, float wy,
                                           const float4* __restrict__ w1x,
                                           const float4* __restrict__ w1y,
                                           const float4* __restrict__ vb1,
                                           const float4* __restrict__ vw2, float b2v) {
    const float C0 = (float)(0.5 / 1025.0);
    float px = (wx / 1025.0f + C0) * 2.0f - 1.0f;
    float py = (wy / 1025.0f + C0) * 2.0f - 1.0f;
    float a0 = 0.f, a1 = 0.f, a2 = 0.f, a3 = 0.f;
#pragma unroll 8
    for (int q = 0; q < HID / 4; ++q) {
        float4 a = w1x[q], b = w1y[q], c = vb1[q], d = vw2[q];
        float h0 = px * a.x + py * b.x + c.x;
        float h1 = px * a.y + py * b.y + c.y;
        float h2 = px * a.z + py * b.z + c.z;
        float h3 = px * a.w + py * b.w + c.w;
        h0 = h0 > 0.f ? h0 : 0.f;
        h1 = h1 > 0.f ? h1 : 0.f;
        h2 = h2 > 0.f ? h2 : 0.f;
        h3 = h3 > 0.f ? h3 : 0.f;
        a0 += h0 * d.x;
        a1 += h1 * d.y;
        a2 += h2 * d.z;
        a3 += h3 * d.w;
    }
    float x = ((a0 + a1) + (a2 + a3)) + b2v;
    float r;
    if (x >= 0.f) { r = 1.0f / (1.0f + expf(-x)); }
    else { float e = expf(x); r = e / (1.0f + e); }
    return r;
}

// ---------------- block exclusive scan helper (256 threads) ----------------
__device__ __forceinline__ uint32_t block_exscan_256(uint32_t v, volatile uint32_t* lds4) {
    int lane = threadIdx.x & 63, w = threadIdx.x >> 6;
    uint32_t inc = v;
#pragma unroll
    for (int d = 1; d < 64; d <<= 1) {
        uint32_t o = (uint32_t)__shfl_up((int)inc, d, 64);
        if (lane >= d) inc += o;
    }
    if (lane == 63) lds4[w] = inc;
    __syncthreads();
    uint32_t woff = 0;
    for (int i = 0; i < w; ++i) woff += lds4[i];
    return woff + inc - v;
}

// ---------------- scan core: given per-thread bin counts, find digit of k-th largest ----------------
__device__ __forceinline__ void scan_find(const uint32_t* cnts, int C, int NB,
                                          uint32_t rem_in, uint32_t pfx_in, int shift,
                                          volatile uint32_t* lds4, volatile uint32_t* ldspair,
                                          uint32_t* outp, uint32_t* outr) {
    int tid = threadIdx.x;
    int b0 = NB - (tid + 1) * C;   // thread 0 owns TOP bins
    uint32_t s = 0;
    for (int k = 0; k < C; ++k) s += cnts[k];
    uint32_t excl = block_exscan_256(s, lds4);
    uint32_t run = excl;
    for (int k = 0; k < C; ++k) {
        uint32_t c = cnts[C - 1 - k];   // descending bin order within thread
        if (rem_in > run && rem_in <= run + c) {
            ldspair[0] = (pfx_in << shift) | (uint32_t)(b0 + C - 1 - k);
            ldspair[1] = rem_in - run;
        }
        run += c;
    }
    __syncthreads();
    *outp = ldspair[0];
    *outr = ldspair[1];
}

// normal loads (histogram from a PREVIOUS dispatch — dispatch boundary made it visible)
__device__ void scan_hist_norm(const uint32_t* __restrict__ hist, int NB,
                               uint32_t rem_in, uint32_t pfx_in, int shift,
                               volatile uint32_t* lds4, volatile uint32_t* ldspair,
                               uint32_t* outp, uint32_t* outr) {
    int tid = threadIdx.x;
    int C = NB >> 8;
    int b0 = NB - (tid + 1) * C;
    uint32_t cnts[8];
#pragma unroll
    for (int k = 0; k < 8; ++k) cnts[k] = 0;
    for (int rep = 0; rep < NREP; ++rep) {
        const uint4* p = (const uint4*)(hist + (size_t)rep * NB + b0);
#pragma unroll
        for (int g = 0; g < 2; ++g) {
            if (g * 4 < C) {
                uint4 v = p[g];
                cnts[g * 4 + 0] += v.x;
                cnts[g * 4 + 1] += v.y;
                cnts[g * 4 + 2] += v.z;
                cnts[g * 4 + 3] += v.w;
            }
        }
    }
    scan_find(cnts, C, NB, rem_in, pfx_in, shift, lds4, ldspair, outp, outr);
}

// agent-scope atomic loads (histogram built by THIS dispatch's atomics — bypass stale L2)
__device__ void scan_hist_atomic(const uint32_t* __restrict__ hist, int NB,
                                 uint32_t rem_in, uint32_t pfx_in, int shift,
                                 volatile uint32_t* lds4, volatile uint32_t* ldspair,
                                 uint32_t* outp, uint32_t* outr) {
    int tid = threadIdx.x;
    int C = NB >> 8;
    int b0 = NB - (tid + 1) * C;
    uint32_t cnts[8];
#pragma unroll
    for (int k = 0; k < 8; ++k) cnts[k] = 0;
    for (int rep = 0; rep < NREP; ++rep) {
        const uint32_t* p = hist + (size_t)rep * NB + b0;
        for (int k = 0; k < C; ++k) cnts[k] += ALOAD32(&p[k]);
    }
    scan_find(cnts, C, NB, rem_in, pfx_in, shift, lds4, ldspair, outp, outr);
}

// ---------------- eval0 + zero all per-stage buffers ----------------
__global__ __launch_bounds__(256) void k_eval0z(const float* __restrict__ w1, const float* __restrict__ b1,
                                                const float* __restrict__ w2, const float* __restrict__ b2,
                                                float* __restrict__ occ, uint32_t* __restrict__ zbuf, int zcount) {
    __shared__ alignas(16) float sw1[2 * HID];
    __shared__ alignas(16) float sb1[HID];
    __shared__ alignas(16) float sw2[HID];
    int tid = threadIdx.x;
    for (int i = tid; i < 2 * HID; i += 256) sw1[i] = w1[i];
    sb1[tid] = b1[tid];
    sw2[tid] = w2[tid];
    __syncthreads();
    int gtid = blockIdx.x * 256 + tid;
    int nthreads = gridDim.x * 256;
    for (int i = gtid; i < zcount; i += nthreads) zbuf[i] = 0;
    for (int n = gtid; n < 65 * 65; n += nthreads) {
        int i = n / 65, j = n % 65;
        occ[n] = mlp_eval4(16.0f * (float)j, 16.0f * (float)i,
                           (const float4*)sw1, (const float4*)(sw1 + HID),
                           (const float4*)sb1, (const float4*)sw2, b2[0]);
    }
}

// ---------------- upsample 2x + key + msb-11 hist (separate dispatch: bulk writes need boundary) ----
__global__ __launch_bounds__(256) void k_upkey(const float* __restrict__ in, int rp,
                                               float* __restrict__ outg, int r, int nb, int bstride,
                                               uint32_t* __restrict__ keys,
                                               uint32_t* __restrict__ histA) {
    __shared__ uint32_t hist[2048];
    int tid = threadIdx.x;
    for (int k = tid; k < 2048; k += 256) hist[k] = 0;
    __syncthreads();
    int N = r * r;
    int lane = tid & 63;
    int gstride = gridDim.x * 256;
    for (int n0 = blockIdx.x * 256; n0 < N; n0 += gstride) {
        int n = n0 + tid;
        bool act = n < N;
        uint32_t key = 0;
        if (act) {
            int i = n / r, j = n % r;
            int i2 = i >> 1, j2 = j >> 1;
            float v;
            if ((i & 1) == 0) {
                if ((j & 1) == 0) {
                    v = in[i2 * rp + j2];
                } else {
                    float a = in[i2 * rp + j2], b = in[i2 * rp + j2 + 1];
                    v = a * 0.5f + b * 0.5f;
                }
            } else {
                if ((j & 1) == 0) {
                    float a = in[i2 * rp + j2], b = in[(i2 + 1) * rp + j2];
                    v = a * 0.5f + b * 0.5f;
                } else {
                    float a = in[i2 * rp + j2],      c = in[i2 * rp + j2 + 1];
                    float b = in[(i2 + 1) * rp + j2], d = in[(i2 + 1) * rp + j2 + 1];
                    float t1 = a * 0.5f + b * 0.5f;
                    float t2 = c * 0.5f + d * 0.5f;
                    v = t1 * 0.5f + t2 * 0.5f;
                }
            }
            for (int k = 0; k < nb; ++k) outg[(size_t)k * bstride + n] = v;
            float unc = -fabsf(v - 0.5f);
            uint32_t u = __float_as_uint(unc);
            key = (u & 0x80000000u) ? ~u : (u | 0x80000000u);
            keys[n] = key;
        }
        uint32_t bin = key >> 21;
        unsigned long long m = __ballot(act);
        if (m) {
            int leader = __ffsll(m) - 1;
            uint32_t lbin = (uint32_t)__shfl((int)bin, leader, 64);
            unsigned long long smk = __ballot(act && bin == lbin);
            if (smk == m) {
                if (lane == leader) atomicAdd(&hist[lbin], (uint32_t)__popcll(m));
            } else if (act) {
                atomicAdd(&hist[bin], 1u);
            }
        }
    }
    __syncthreads();
    uint32_t* myrep = histA + (size_t)(blockIdx.x & (NREP - 1)) * 2048;
    for (int k = tid; k < 2048; k += 256) {
        uint32_t c = hist[k];
        if (c) atomicAdd(&myrep[k], c);
    }
}

// ---------------- mega: radix passes 2+3 (last-block scans), tie lookback, select, eval ----------------
__global__ __launch_bounds__(256, 2) void k_mega(const uint32_t* __restrict__ keys, int N, int seglen,
                                                 uint32_t npt, uint32_t* __restrict__ sm,
                                                 int r, float stride,
                                                 float* __restrict__ occ, int nb, int bstride,
                                                 const float* __restrict__ w1, const float* __restrict__ b1,
                                                 const float* __restrict__ w2, const float* __restrict__ b2) {
    __shared__ alignas(16) float sw1[2 * HID];
    __shared__ alignas(16) float sb1[HID];
    __shared__ alignas(16) float sw2[HID];
    __shared__ uint32_t lh[2048];
    __shared__ uint32_t lds4[4];
    __shared__ uint32_t ldspair[2];
    __shared__ uint32_t wcnt[4];
    __shared__ uint32_t islast_s;
    __shared__ uint32_t selcnt;
    __shared__ uint32_t selidx[SELMAX];

    int tid = threadIdx.x, lane = tid & 63, w = tid >> 6;
    int blk = blockIdx.x;
    int gstride = MBLK * 256;
    for (int i = tid; i < 2 * HID; i += 256) sw1[i] = w1[i];
    sb1[tid] = b1[tid];
    sw2[tid] = w2[tid];
    if (tid == 0) selcnt = 0;

    uint32_t* histA = sm + HA_OFF;
    uint32_t* histB = sm + HB_OFF;
    uint32_t* histC = sm + HC_OFF;
    unsigned long long* slot1 = (unsigned long long*)(sm + SLOT1_OFF);
    unsigned long long* slot2 = (unsigned long long*)(sm + SLOT2_OFF);
    uint32_t* ctr1 = sm + CTR1_OFF;
    uint32_t* ctr2 = sm + CTR2_OFF;
    uint32_t* blkT = sm + BLKT_OFF;

    // ---- scan A (histA from previous dispatch; redundant per block, normal vectorized loads) ----
    uint32_t pfx1, rem1;
    scan_hist_norm(histA, 2048, npt, 0u, 0, lds4, ldspair, &pfx1, &rem1);

    // ---- phase 1: filtered mid-11 histogram -> histB ----
    __syncthreads();
    for (int k = tid; k < 2048; k += 256) lh[k] = 0;
    __syncthreads();
    for (int base = blk * 256; base < N; base += gstride) {
        int n = base + tid;
        bool inb = n < N;
        uint32_t key = inb ? keys[n] : 0u;
        bool flt = inb && ((key >> 21) == pfx1);
        uint32_t bin = (key >> 10) & 0x7FFu;
        unsigned long long m = __ballot(flt);
        if (m) {
            int leader = __ffsll(m) - 1;
            uint32_t lbin = (uint32_t)__shfl((int)bin, leader, 64);
            unsigned long long smk = __ballot(flt && bin == lbin);
            if (smk == m) {
                if (lane == leader) atomicAdd(&lh[lbin], (uint32_t)__popcll(m));
            } else if (flt) {
                atomicAdd(&lh[bin], 1u);
            }
        }
    }
    __syncthreads();
    {
        uint32_t* myrep = histB + (size_t)(blk & (NREP - 1)) * 2048;
        for (int k = tid; k < 2048; k += 256) {
            uint32_t c = lh[k];
            if (c) atomicAdd(&myrep[k], c);
        }
    }
    __syncthreads();  // drains flush atomics (vmcnt) before counter bump
    if (tid == 0) {
        uint32_t old = __hip_atomic_fetch_add(ctr1, 1u, __ATOMIC_RELAXED, __HIP_MEMORY_SCOPE_AGENT);
        islast_s = (old == (uint32_t)(MBLK - 1));
    }
    __syncthreads();
    if (islast_s) {   // block-uniform branch: __syncthreads inside is legal
        uint32_t p2, r2;
        scan_hist_atomic(histB, 2048, rem1, pfx1, 11, lds4, ldspair, &p2, &r2);
        if (tid == 0) {
            unsigned long long v = ((unsigned long long)p2 << 32) | (unsigned long long)(r2 | FLAG31);
            ASTORE64(slot1, v);
        }
    }
    uint32_t pfx2, rem2;
    {
        unsigned long long v;
        for (;;) {
            v = ALOAD64(slot1);
            if ((uint32_t)v & FLAG31) break;
            __builtin_amdgcn_s_sleep(2);
        }
        pfx2 = (uint32_t)(v >> 32);
        rem2 = (uint32_t)v & 0x7FFFFFFFu;
    }

    // ---- phase 2: filtered low-10 histogram -> histC ----
    __syncthreads();
    for (int k = tid; k < 1024; k += 256) lh[k] = 0;
    __syncthreads();
    for (int base = blk * 256; base < N; base += gstride) {
        int n = base + tid;
        bool inb = n < N;
        uint32_t key = inb ? keys[n] : 0u;
        bool flt = inb && ((key >> 10) == pfx2);
        uint32_t bin = key & 0x3FFu;
        unsigned long long m = __ballot(flt);
        if (m) {
            int leader = __ffsll(m) - 1;
            uint32_t lbin = (uint32_t)__shfl((int)bin, leader, 64);
            unsigned long long smk = __ballot(flt && bin == lbin);
            if (smk == m) {
                if (lane == leader) atomicAdd(&lh[lbin], (uint32_t)__popcll(m));
            } else if (flt) {
                atomicAdd(&lh[bin], 1u);
            }
        }
    }
    __syncthreads();
    {
        uint32_t* myrep = histC + (size_t)(blk & (NREP - 1)) * 1024;
        for (int k = tid; k < 1024; k += 256) {
            uint32_t c = lh[k];
            if (c) atomicAdd(&myrep[k], c);
        }
    }
    __syncthreads();
    if (tid == 0) {
        uint32_t old = __hip_atomic_fetch_add(ctr2, 1u, __ATOMIC_RELAXED, __HIP_MEMORY_SCOPE_AGENT);
        islast_s = (old == (uint32_t)(MBLK - 1));
    }
    __syncthreads();
    if (islast_s) {
        uint32_t K_, t_;
        scan_hist_atomic(histC, 1024, rem2, pfx2, 10, lds4, ldspair, &K_, &t_);
        if (tid == 0) {
            unsigned long long v = ((unsigned long long)K_ << 32) | (unsigned long long)(t_ | FLAG31);
            ASTORE64(slot2, v);
        }
    }
    uint32_t K, t;
    {
        unsigned long long v;
        for (;;) {
            v = ALOAD64(slot2);
            if ((uint32_t)v & FLAG31) break;
            __builtin_amdgcn_s_sleep(2);
        }
        K = (uint32_t)(v >> 32);
        t = (uint32_t)v & 0x7FFFFFFFu;
    }

    // ---- phase 3: per-wave tie counts + per-block decoupled lookback (publish BEFORE spin) ----
    int wv = blk * 4 + w;
    int s0 = wv * seglen;
    int s1 = s0 + seglen; if (s1 > N) s1 = N;
    {
        uint32_t tcnt = 0;
        for (int base = s0; base < s1; base += 64) {
            int n = base + lane;
            if (n < s1) tcnt += (keys[n] == K) ? 1u : 0u;
        }
#pragma unroll
        for (int d = 32; d; d >>= 1) tcnt += (uint32_t)__shfl_down((int)tcnt, d, 64);
        if (lane == 0) wcnt[w] = tcnt;
    }
    __syncthreads();
    if (tid == 0) {
        uint32_t tot = wcnt[0] + wcnt[1] + wcnt[2] + wcnt[3];
        ASTORE32(&blkT[blk], tot | FLAG31);
    }
    uint32_t bp = 0;
    for (int i = lane; i < blk; i += 64) {
        uint32_t v;
        for (;;) {
            v = ALOAD32(&blkT[i]);
            if (v & FLAG31) break;
            __builtin_amdgcn_s_sleep(2);
        }
        bp += v & 0x7FFFFFFFu;
    }
#pragma unroll
    for (int d = 32; d; d >>= 1) bp += (uint32_t)__shfl_down((int)bp, d, 64);
    bp = (uint32_t)__shfl((int)bp, 0, 64);
    uint32_t tp = bp;
    for (int ww = 0; ww < w; ++ww) tp += wcnt[ww];

    // ---- phase 4: select (exact top-k, index-ascending ties) -> LDS compaction ----
    uint32_t tie_run = tp;
    unsigned long long lowmask = (lane == 63) ? ~0ull >> 1 : ((1ull << lane) - 1ull);
    for (int base = s0; base < s1; base += 64) {
        int n = base + lane;
        bool inb = n < s1;
        uint32_t key = inb ? keys[n] : 0u;
        bool gt = inb && (key > K);
        bool tie = inb && (key == K);
        unsigned long long tm = __ballot(tie);
        uint32_t trank = tie_run + (uint32_t)__popcll(tm & lowmask);
        bool sel = gt || (tie && trank < t);
        unsigned long long smk = __ballot(sel);
        if (smk) {
            int leader = __ffsll(smk) - 1;
            uint32_t wbase = 0;
            if (lane == leader) wbase = atomicAdd(&selcnt, (uint32_t)__popcll(smk));
            wbase = (uint32_t)__shfl((int)wbase, leader, 64);
            if (sel) selidx[wbase + (uint32_t)__popcll(smk & lowmask)] = (uint32_t)n;
        }
        tie_run += (uint32_t)__popcll(tm);
    }
    __syncthreads();

    // ---- phase 5: dense eval, 4 points per thread per weight sweep ----
    uint32_t cnt = selcnt;
    float vb2 = b2[0];
    const float4* w1x = (const float4*)sw1;
    const float4* w1y = (const float4*)(sw1 + HID);
    const float4* vb1 = (const float4*)sb1;
    const float4* vw2 = (const float4*)sw2;
    const float C0 = (float)(0.5 / 1025.0);
    for (uint32_t bb = 0; bb < cnt; bb += 1024) {
        uint32_t i0 = bb + tid, i1 = i0 + 256, i2 = i0 + 512, i3 = i0 + 768;
        bool v0 = i0 < cnt, v1 = i1 < cnt, v2 = i2 < cnt, v3 = i3 < cnt;
        int nA = v0 ? (int)selidx[i0] : 0;
        int nB = v1 ? (int)selidx[i1] : 0;
        int nC = v2 ? (int)selidx[i2] : 0;
        int nD = v3 ? (int)selidx[i3] : 0;
        int iA = nA / r, jA = nA % r;
        int iB = nB / r, jB = nB % r;
        int iC = nC / r, jC = nC % r;
        int iD = nD / r, jD = nD % r;
        float px0 = ((stride * (float)jA) / 1025.0f + C0) * 2.0f - 1.0f;
        float py0 = ((stride * (float)iA) / 1025.0f + C0) * 2.0f - 1.0f;
        float px1 = ((stride * (float)jB) / 1025.0f + C0) * 2.0f - 1.0f;
        float py1 = ((stride * (float)iB) / 1025.0f + C0) * 2.0f - 1.0f;
        float px2 = ((stride * (float)jC) / 1025.0f + C0) * 2.0f - 1.0f;
        float py2 = ((stride * (float)iC) / 1025.0f + C0) * 2.0f - 1.0f;
        float px3 = ((stride * (float)jD) / 1025.0f + C0) * 2.0f - 1.0f;
        float py3 = ((stride * (float)iD) / 1025.0f + C0) * 2.0f - 1.0f;
        float4 A0 = {0, 0, 0, 0}, A1 = {0, 0, 0, 0}, A2 = {0, 0, 0, 0}, A3 = {0, 0, 0, 0};
#pragma unroll 4
        for (int q = 0; q < HID / 4; ++q) {
            float4 a = w1x[q], b = w1y[q], c = vb1[q], d = vw2[q];
#define STEP(P, AX) {                                              \
            float h0 = px##P * a.x + py##P * b.x + c.x;            \
            float h1 = px##P * a.y + py##P * b.y + c.y;            \
            float h2 = px##P * a.z + py##P * b.z + c.z;            \
            float h3 = px##P * a.w + py##P * b.w + c.w;            \
            h0 = h0 > 0.f ? h0 : 0.f;                              \
            h1 = h1 > 0.f ? h1 : 0.f;                              \
            h2 = h2 > 0.f ? h2 : 0.f;                              \
            h3 = h3 > 0.f ? h3 : 0.f;                              \
            AX.x += h0 * d.x; AX.y += h1 * d.y;                    \
            AX.z += h2 * d.z; AX.w += h3 * d.w; }
            STEP(0, A0) STEP(1, A1) STEP(2, A2) STEP(3, A3)
#undef STEP
        }
#define FIN(VQ, AX, NP) if (VQ) {                                  \
        float x = ((AX.x + AX.y) + (AX.z + AX.w)) + vb2;           \
        float rr;                                                  \
        if (x >= 0.f) { rr = 1.0f / (1.0f + expf(-x)); }           \
        else { float e = expf(x); rr = e / (1.0f + e); }           \
        for (int k = 0; k < nb; ++k) occ[(size_t)k * bstride + NP] = rr; }
        FIN(v0, A0, nA) FIN(v1, A1, nB) FIN(v2, A2, nC) FIN(v3, A3, nD)
#undef FIN
    }
}

// ---------------- fallback-only broadcast (used when d_ws is too small) ----------------
__global__ __launch_bounds__(256) void k_bcast(const float* __restrict__ src, float* __restrict__ dst, int N) {
    int q = blockIdx.x * 256 + threadIdx.x;
    int n = q * 4;
    if (n + 3 < N) {
        float4 v = *(const float4*)(src + n);
#pragma unroll
        for (int k = 0; k < 8; ++k) *(float4*)(dst + (size_t)k * N + n) = v;
    } else if (n < N) {
        for (int m = n; m < N; ++m) {
            float v = src[m];
#pragma unroll
            for (int k = 0; k < 8; ++k) dst[(size_t)k * N + m] = v;
        }
    }
}

extern "C" void kernel_launch(void* const* d_in, const int* in_sizes, int n_in,
                              void* d_out, int out_size, void* d_ws, size_t ws_size,
                              hipStream_t stream) {
    const float* w1 = (const float*)d_in[0];
    const float* b1 = (const float*)d_in[1];
    const float* w2 = (const float*)d_in[2];
    const float* b2 = (const float*)d_in[3];
    float* out = (float*)d_out;

    const size_t A = (((size_t)NMAXPIX * 4) + 255) & ~(size_t)255;  // one grid buffer
    const size_t SMALL_BYTES = (size_t)4 * STAGE_U32 * 4;            // 4 stages (~338 KB)
    const size_t need = 3 * A + SMALL_BYTES;

    int fused8 = (ws_size >= need);
    char* base = fused8 ? (char*)d_ws : (char*)d_out;
    float* buf0 = (float*)(base);
    float* buf1 = (float*)(base + A);
    uint32_t* keys = (uint32_t*)(base + 2 * A);
    uint32_t* smallb = (uint32_t*)(base + 3 * A);

    // dispatch 1: zero all stage buffers (incl. flags/counters poisoned to 0xAA) + dense 65x65 eval
    k_eval0z<<<dim3(512), dim3(256), 0, stream>>>(w1, b1, w2, b2, buf0, smallb, 4 * STAGE_U32);

    const int resA[5] = {65, 129, 257, 513, 1025};
    const int nptA[5] = {0, 4096, 16384, 65536, 262144};
    float* cur = buf0;
    float* nxt = buf1;
    for (int s = 1; s < 5; ++s) {
        int rp = resA[s - 1], r = resA[s];
        int N = r * r;
        uint32_t npt = (uint32_t)nptA[s];
        uint32_t* sm = smallb + (size_t)(s - 1) * STAGE_U32;
        int nb1 = (N + 255) / 256;
        int nbu = nb1 < 1024 ? nb1 : 1024;
        int seglen = (N + NSEG - 1) / NSEG;
        float stride = 1024.0f / (float)(r - 1);

        int last = (s == 4);
        float* stage_out = (last && fused8) ? out : nxt;
        int nb = (last && fused8) ? 8 : 1;
        int bstride = (last && fused8) ? NMAXPIX : 0;

        k_upkey<<<dim3(nbu), dim3(256), 0, stream>>>(cur, rp, stage_out, r, nb, bstride, keys, sm + HA_OFF);
        k_mega<<<dim3(MBLK), dim3(256), 0, stream>>>(keys, N, seglen, npt, sm, r, stride,
                                                     stage_out, nb, bstride, w1, b1, w2, b2);
        if (!(last && fused8)) { float* tmp = cur; cur = nxt; nxt = tmp; }
    }
    if (!fused8) {
        k_bcast<<<dim3(((NMAXPIX + 3) / 4 + 255) / 256), dim3(256), 0, stream>>>(cur, out, NMAXPIX);
    }
}

// Round 10
// 310.133 us; speedup vs baseline: 1.0309x; 1.0309x over previous
//
#include <hip/hip_runtime.h>
#include <stdint.h>

#define HID 256
#define NMAXPIX (1025 * 1025)
#define NREP 4      // histogram replicas, replica-major
#define MBLK 512    // mega grid (co-resident: 2 blocks/CU x 256 CU)
#define NSEG (MBLK * 4)
#define SELMAX 2112
#define FLAG31 0x80000000u

// per-stage small-buffer layout (u32 units)
#define HA_OFF    0        // 4 x 2048
#define HB_OFF    8192     // 4 x 2048
#define HC_OFF    16384    // 4 x 1024
#define SLOT1_OFF 20480    // u64 (pfx2, rem2|flag)
#define SLOT2_OFF 20482    // u64 (K, t|flag)
#define CTR1_OFF  20484
#define CTR2_OFF  20485
#define BLKT_OFF  20544    // 512 lookback slots
#define STAGE_U32 21120

#define ALOAD32(p)  __hip_atomic_load((p), __ATOMIC_RELAXED, __HIP_MEMORY_SCOPE_AGENT)
#define ALOAD64(p)  __hip_atomic_load((p), __ATOMIC_RELAXED, __HIP_MEMORY_SCOPE_AGENT)
#define ASTORE32(p, v) __hip_atomic_store((p), (v), __ATOMIC_RELAXED, __HIP_MEMORY_SCOPE_AGENT)
#define ASTORE64(p, v) __hip_atomic_store((p), (v), __ATOMIC_RELAXED, __HIP_MEMORY_SCOPE_AGENT)

// ---------------- MLP eval (single point), float4 LDS weight reads ----------------
__device__ __forceinline__ float mlp_eval4(float wx, float wy,
                                           const float4* __restrict__ w1x,
                                           const float4* __restrict__ w1y,
                                           const float4* __restrict__ vb1,
                                           const float4* __restrict__ vw2, float b2v) {
    const float C0 = (float)(0.5 / 1025.0);
    float px = (wx / 1025.0f + C0) * 2.0f - 1.0f;
    float py = (wy / 1025.0f + C0) * 2.0f - 1.0f;
    float a0 = 0.f, a1 = 0.f, a2 = 0.f, a3 = 0.f;
#pragma unroll 8
    for (int q = 0; q < HID / 4; ++q) {
        float4 a = w1x[q], b = w1y[q], c = vb1[q], d = vw2[q];
        float h0 = px * a.x + py * b.x + c.x;
        float h1 = px * a.y + py * b.y + c.y;
        float h2 = px * a.z + py * b.z + c.z;
        float h3 = px * a.w + py * b.w + c.w;
        h0 = h0 > 0.f ? h0 : 0.f;
        h1 = h1 > 0.f ? h1 : 0.f;
        h2 = h2 > 0.f ? h2 : 0.f;
        h3 = h3 > 0.f ? h3 : 0.f;
        a0 += h0 * d.x;
        a1 += h1 * d.y;
        a2 += h2 * d.z;
        a3 += h3 * d.w;
    }
    float x = ((a0 + a1) + (a2 + a3)) + b2v;
    float r;
    if (x >= 0.f) { r = 1.0f / (1.0f + expf(-x)); }
    else { float e = expf(x); r = e / (1.0f + e); }
    return r;
}

// ---------------- block exclusive scan helper (256 threads) ----------------
__device__ __forceinline__ uint32_t block_exscan_256(uint32_t v, volatile uint32_t* lds4) {
    int lane = threadIdx.x & 63, w = threadIdx.x >> 6;
    uint32_t inc = v;
#pragma unroll
    for (int d = 1; d < 64; d <<= 1) {
        uint32_t o = (uint32_t)__shfl_up((int)inc, d, 64);
        if (lane >= d) inc += o;
    }
    if (lane == 63) lds4[w] = inc;
    __syncthreads();
    uint32_t woff = 0;
    for (int i = 0; i < w; ++i) woff += lds4[i];
    return woff + inc - v;
}

// ---------------- scan core: given per-thread bin counts, find digit of k-th largest ----------------
__device__ __forceinline__ void scan_find(const uint32_t* cnts, int C, int NB,
                                          uint32_t rem_in, uint32_t pfx_in, int shift,
                                          volatile uint32_t* lds4, volatile uint32_t* ldspair,
                                          uint32_t* outp, uint32_t* outr) {
    int tid = threadIdx.x;
    int b0 = NB - (tid + 1) * C;   // thread 0 owns TOP bins
    uint32_t s = 0;
    for (int k = 0; k < C; ++k) s += cnts[k];
    uint32_t excl = block_exscan_256(s, lds4);
    uint32_t run = excl;
    for (int k = 0; k < C; ++k) {
        uint32_t c = cnts[C - 1 - k];   // descending bin order within thread
        if (rem_in > run && rem_in <= run + c) {
            ldspair[0] = (pfx_in << shift) | (uint32_t)(b0 + C - 1 - k);
            ldspair[1] = rem_in - run;
        }
        run += c;
    }
    __syncthreads();
    *outp = ldspair[0];
    *outr = ldspair[1];
}

// normal loads (histogram from a PREVIOUS dispatch — dispatch boundary made it visible)
__device__ void scan_hist_norm(const uint32_t* __restrict__ hist, int NB,
                               uint32_t rem_in, uint32_t pfx_in, int shift,
                               volatile uint32_t* lds4, volatile uint32_t* ldspair,
                               uint32_t* outp, uint32_t* outr) {
    int tid = threadIdx.x;
    int C = NB >> 8;
    int b0 = NB - (tid + 1) * C;
    uint32_t cnts[8];
#pragma unroll
    for (int k = 0; k < 8; ++k) cnts[k] = 0;
    for (int rep = 0; rep < NREP; ++rep) {
        const uint4* p = (const uint4*)(hist + (size_t)rep * NB + b0);
#pragma unroll
        for (int g = 0; g < 2; ++g) {
            if (g * 4 < C) {
                uint4 v = p[g];
                cnts[g * 4 + 0] += v.x;
                cnts[g * 4 + 1] += v.y;
                cnts[g * 4 + 2] += v.z;
                cnts[g * 4 + 3] += v.w;
            }
        }
    }
    scan_find(cnts, C, NB, rem_in, pfx_in, shift, lds4, ldspair, outp, outr);
}

// agent-scope atomic loads (histogram built by THIS dispatch's atomics — bypass stale L2)
__device__ void scan_hist_atomic(const uint32_t* __restrict__ hist, int NB,
                                 uint32_t rem_in, uint32_t pfx_in, int shift,
                                 volatile uint32_t* lds4, volatile uint32_t* ldspair,
                                 uint32_t* outp, uint32_t* outr) {
    int tid = threadIdx.x;
    int C = NB >> 8;
    int b0 = NB - (tid + 1) * C;
    uint32_t cnts[8];
#pragma unroll
    for (int k = 0; k < 8; ++k) cnts[k] = 0;
    for (int rep = 0; rep < NREP; ++rep) {
        const uint32_t* p = hist + (size_t)rep * NB + b0;
        for (int k = 0; k < C; ++k) cnts[k] += ALOAD32(&p[k]);
    }
    scan_find(cnts, C, NB, rem_in, pfx_in, shift, lds4, ldspair, outp, outr);
}

// ---------------- eval0 + zero all per-stage buffers ----------------
__global__ __launch_bounds__(256) void k_eval0z(const float* __restrict__ w1, const float* __restrict__ b1,
                                                const float* __restrict__ w2, const float* __restrict__ b2,
                                                float* __restrict__ occ, uint32_t* __restrict__ zbuf, int zcount) {
    __shared__ alignas(16) float sw1[2 * HID];
    __shared__ alignas(16) float sb1[HID];
    __shared__ alignas(16) float sw2[HID];
    int tid = threadIdx.x;
    for (int i = tid; i < 2 * HID; i += 256) sw1[i] = w1[i];
    sb1[tid] = b1[tid];
    sw2[tid] = w2[tid];
    __syncthreads();
    int gtid = blockIdx.x * 256 + tid;
    int nthreads = gridDim.x * 256;
    for (int i = gtid; i < zcount; i += nthreads) zbuf[i] = 0;
    for (int n = gtid; n < 65 * 65; n += nthreads) {
        int i = n / 65, j = n % 65;
        occ[n] = mlp_eval4(16.0f * (float)j, 16.0f * (float)i,
                           (const float4*)sw1, (const float4*)(sw1 + HID),
                           (const float4*)sb1, (const float4*)sw2, b2[0]);
    }
}

// ---------------- upsample 2x + key + msb-11 hist (separate dispatch: bulk writes need boundary) ----
__global__ __launch_bounds__(256) void k_upkey(const float* __restrict__ in, int rp,
                                               float* __restrict__ outg, int r, int nb, int bstride,
                                               uint32_t* __restrict__ keys,
                                               uint32_t* __restrict__ histA) {
    __shared__ uint32_t hist[2048];
    int tid = threadIdx.x;
    for (int k = tid; k < 2048; k += 256) hist[k] = 0;
    __syncthreads();
    int N = r * r;
    int lane = tid & 63;
    int gstride = gridDim.x * 256;
    for (int n0 = blockIdx.x * 256; n0 < N; n0 += gstride) {
        int n = n0 + tid;
        bool act = n < N;
        uint32_t key = 0;
        if (act) {
            int i = n / r, j = n % r;
            int i2 = i >> 1, j2 = j >> 1;
            float v;
            if ((i & 1) == 0) {
                if ((j & 1) == 0) {
                    v = in[i2 * rp + j2];
                } else {
                    float a = in[i2 * rp + j2], b = in[i2 * rp + j2 + 1];
                    v = a * 0.5f + b * 0.5f;
                }
            } else {
                if ((j & 1) == 0) {
                    float a = in[i2 * rp + j2], b = in[(i2 + 1) * rp + j2];
                    v = a * 0.5f + b * 0.5f;
                } else {
                    float a = in[i2 * rp + j2],      c = in[i2 * rp + j2 + 1];
                    float b = in[(i2 + 1) * rp + j2], d = in[(i2 + 1) * rp + j2 + 1];
                    float t1 = a * 0.5f + b * 0.5f;
                    float t2 = c * 0.5f + d * 0.5f;
                    v = t1 * 0.5f + t2 * 0.5f;
                }
            }
            for (int k = 0; k < nb; ++k) outg[(size_t)k * bstride + n] = v;
            float unc = -fabsf(v - 0.5f);
            uint32_t u = __float_as_uint(unc);
            key = (u & 0x80000000u) ? ~u : (u | 0x80000000u);
            keys[n] = key;
        }
        uint32_t bin = key >> 21;
        unsigned long long m = __ballot(act);
        if (m) {
            int leader = __ffsll(m) - 1;
            uint32_t lbin = (uint32_t)__shfl((int)bin, leader, 64);
            unsigned long long smk = __ballot(act && bin == lbin);
            if (smk == m) {
                if (lane == leader) atomicAdd(&hist[lbin], (uint32_t)__popcll(m));
            } else if (act) {
                atomicAdd(&hist[bin], 1u);
            }
        }
    }
    __syncthreads();
    uint32_t* myrep = histA + (size_t)(blockIdx.x & (NREP - 1)) * 2048;
    for (int k = tid; k < 2048; k += 256) {
        uint32_t c = hist[k];
        if (c) atomicAdd(&myrep[k], c);
    }
}

// ---------------- mega: radix passes 2+3 (last-block scans), tie lookback, select, eval ----------------
__global__ __launch_bounds__(256, 2) void k_mega(const uint32_t* __restrict__ keys, int N, int seglen,
                                                 uint32_t npt, uint32_t* __restrict__ sm,
                                                 int r, float stride,
                                                 float* __restrict__ occ, int nb, int bstride,
                                                 const float* __restrict__ w1, const float* __restrict__ b1,
                                                 const float* __restrict__ w2, const float* __restrict__ b2) {
    __shared__ alignas(16) float sw1[2 * HID];
    __shared__ alignas(16) float sb1[HID];
    __shared__ alignas(16) float sw2[HID];
    __shared__ uint32_t lh[2048];
    __shared__ uint32_t lds4[4];
    __shared__ uint32_t ldspair[2];
    __shared__ uint32_t wcnt[4];
    __shared__ uint32_t islast_s;
    __shared__ uint32_t sres[2];     // tid0-spin broadcast
    __shared__ uint32_t bp_s;        // lookback result broadcast
    __shared__ uint32_t selcnt;
    __shared__ uint32_t selidx[SELMAX];

    int tid = threadIdx.x, lane = tid & 63, w = tid >> 6;
    int blk = blockIdx.x;
    int gstride = MBLK * 256;
    for (int i = tid; i < 2 * HID; i += 256) sw1[i] = w1[i];
    sb1[tid] = b1[tid];
    sw2[tid] = w2[tid];
    if (tid == 0) selcnt = 0;

    uint32_t* histA = sm + HA_OFF;
    uint32_t* histB = sm + HB_OFF;
    uint32_t* histC = sm + HC_OFF;
    unsigned long long* slot1 = (unsigned long long*)(sm + SLOT1_OFF);
    unsigned long long* slot2 = (unsigned long long*)(sm + SLOT2_OFF);
    uint32_t* ctr1 = sm + CTR1_OFF;
    uint32_t* ctr2 = sm + CTR2_OFF;
    uint32_t* blkT = sm + BLKT_OFF;

    // ---- scan A (histA from previous dispatch; redundant per block, vectorized loads) ----
    uint32_t pfx1, rem1;
    scan_hist_norm(histA, 2048, npt, 0u, 0, lds4, ldspair, &pfx1, &rem1);

    // ---- phase 1: filtered mid-11 histogram -> histB ----
    __syncthreads();
    for (int k = tid; k < 2048; k += 256) lh[k] = 0;
    __syncthreads();
    for (int base = blk * 256; base < N; base += gstride) {
        int n = base + tid;
        bool inb = n < N;
        uint32_t key = inb ? keys[n] : 0u;
        bool flt = inb && ((key >> 21) == pfx1);
        uint32_t bin = (key >> 10) & 0x7FFu;
        unsigned long long m = __ballot(flt);
        if (m) {
            int leader = __ffsll(m) - 1;
            uint32_t lbin = (uint32_t)__shfl((int)bin, leader, 64);
            unsigned long long smk = __ballot(flt && bin == lbin);
            if (smk == m) {
                if (lane == leader) atomicAdd(&lh[lbin], (uint32_t)__popcll(m));
            } else if (flt) {
                atomicAdd(&lh[bin], 1u);
            }
        }
    }
    __syncthreads();
    {
        uint32_t* myrep = histB + (size_t)(blk & (NREP - 1)) * 2048;
        for (int k = tid; k < 2048; k += 256) {
            uint32_t c = lh[k];
            if (c) atomicAdd(&myrep[k], c);
        }
    }
    __syncthreads();  // drains flush atomics (vmcnt) before counter bump
    if (tid == 0) {
        uint32_t old = __hip_atomic_fetch_add(ctr1, 1u, __ATOMIC_RELAXED, __HIP_MEMORY_SCOPE_AGENT);
        islast_s = (old == (uint32_t)(MBLK - 1));
    }
    __syncthreads();
    if (islast_s) {   // block-uniform branch
        uint32_t p2, r2;
        scan_hist_atomic(histB, 2048, rem1, pfx1, 11, lds4, ldspair, &p2, &r2);
        if (tid == 0) {
            unsigned long long v = ((unsigned long long)p2 << 32) | (unsigned long long)(r2 | FLAG31);
            ASTORE64(slot1, v);
            sres[0] = p2; sres[1] = r2;
        }
    } else if (tid == 0) {  // ONLY tid0 spins (512 spinners, not 131k)
        unsigned long long v;
        for (;;) {
            v = ALOAD64(slot1);
            if ((uint32_t)v & FLAG31) break;
            __builtin_amdgcn_s_sleep(8);
        }
        sres[0] = (uint32_t)(v >> 32);
        sres[1] = (uint32_t)v & 0x7FFFFFFFu;
    }
    __syncthreads();
    uint32_t pfx2 = sres[0], rem2 = sres[1];

    // ---- phase 2: filtered low-10 histogram -> histC ----
    __syncthreads();
    for (int k = tid; k < 1024; k += 256) lh[k] = 0;
    __syncthreads();
    for (int base = blk * 256; base < N; base += gstride) {
        int n = base + tid;
        bool inb = n < N;
        uint32_t key = inb ? keys[n] : 0u;
        bool flt = inb && ((key >> 10) == pfx2);
        uint32_t bin = key & 0x3FFu;
        unsigned long long m = __ballot(flt);
        if (m) {
            int leader = __ffsll(m) - 1;
            uint32_t lbin = (uint32_t)__shfl((int)bin, leader, 64);
            unsigned long long smk = __ballot(flt && bin == lbin);
            if (smk == m) {
                if (lane == leader) atomicAdd(&lh[lbin], (uint32_t)__popcll(m));
            } else if (flt) {
                atomicAdd(&lh[bin], 1u);
            }
        }
    }
    __syncthreads();
    {
        uint32_t* myrep = histC + (size_t)(blk & (NREP - 1)) * 1024;
        for (int k = tid; k < 1024; k += 256) {
            uint32_t c = lh[k];
            if (c) atomicAdd(&myrep[k], c);
        }
    }
    __syncthreads();
    if (tid == 0) {
        uint32_t old = __hip_atomic_fetch_add(ctr2, 1u, __ATOMIC_RELAXED, __HIP_MEMORY_SCOPE_AGENT);
        islast_s = (old == (uint32_t)(MBLK - 1));
    }
    __syncthreads();
    if (islast_s) {
        uint32_t K_, t_;
        scan_hist_atomic(histC, 1024, rem2, pfx2, 10, lds4, ldspair, &K_, &t_);
        if (tid == 0) {
            unsigned long long v = ((unsigned long long)K_ << 32) | (unsigned long long)(t_ | FLAG31);
            ASTORE64(slot2, v);
            sres[0] = K_; sres[1] = t_;
        }
    } else if (tid == 0) {
        unsigned long long v;
        for (;;) {
            v = ALOAD64(slot2);
            if ((uint32_t)v & FLAG31) break;
            __builtin_amdgcn_s_sleep(8);
        }
        sres[0] = (uint32_t)(v >> 32);
        sres[1] = (uint32_t)v & 0x7FFFFFFFu;
    }
    __syncthreads();
    uint32_t K = sres[0], t = sres[1];

    // ---- phase 3: per-wave tie counts + per-block lookback (wave 0 only; publish BEFORE spin) ----
    int wv = blk * 4 + w;
    int s0 = wv * seglen;
    int s1 = s0 + seglen; if (s1 > N) s1 = N;
    {
        uint32_t tcnt = 0;
        for (int base = s0; base < s1; base += 64) {
            int n = base + lane;
            if (n < s1) tcnt += (keys[n] == K) ? 1u : 0u;
        }
#pragma unroll
        for (int d = 32; d; d >>= 1) tcnt += (uint32_t)__shfl_down((int)tcnt, d, 64);
        if (lane == 0) wcnt[w] = tcnt;
    }
    __syncthreads();
    if (w == 0) {   // wave 0 only: publish then lookback over distinct addresses
        if (lane == 0) {
            uint32_t tot = wcnt[0] + wcnt[1] + wcnt[2] + wcnt[3];
            ASTORE32(&blkT[blk], tot | FLAG31);
        }
        uint32_t bp = 0;
        for (int i = lane; i < blk; i += 64) {
            uint32_t v;
            for (;;) {
                v = ALOAD32(&blkT[i]);
                if (v & FLAG31) break;
                __builtin_amdgcn_s_sleep(2);
            }
            bp += v & 0x7FFFFFFFu;
        }
#pragma unroll
        for (int d = 32; d; d >>= 1) bp += (uint32_t)__shfl_down((int)bp, d, 64);
        if (lane == 0) bp_s = bp;
    }
    __syncthreads();
    uint32_t tp = bp_s;
    for (int ww = 0; ww < w; ++ww) tp += wcnt[ww];

    // ---- phase 4: select (exact top-k, index-ascending ties) -> LDS compaction ----
    uint32_t tie_run = tp;
    unsigned long long lowmask = (lane == 63) ? ~0ull >> 1 : ((1ull << lane) - 1ull);
    for (int base = s0; base < s1; base += 64) {
        int n = base + lane;
        bool inb = n < s1;
        uint32_t key = inb ? keys[n] : 0u;
        bool gt = inb && (key > K);
        bool tie = inb && (key == K);
        unsigned long long tm = __ballot(tie);
        uint32_t trank = tie_run + (uint32_t)__popcll(tm & lowmask);
        bool sel = gt || (tie && trank < t);
        unsigned long long smk = __ballot(sel);
        if (smk) {
            int leader = __ffsll(smk) - 1;
            uint32_t wbase = 0;
            if (lane == leader) wbase = atomicAdd(&selcnt, (uint32_t)__popcll(smk));
            wbase = (uint32_t)__shfl((int)wbase, leader, 64);
            if (sel) selidx[wbase + (uint32_t)__popcll(smk & lowmask)] = (uint32_t)n;
        }
        tie_run += (uint32_t)__popcll(tm);
    }
    __syncthreads();

    // ---- phase 5: dense eval, 4 points per thread per weight sweep ----
    uint32_t cnt = selcnt;
    float vb2 = b2[0];
    const float4* w1x = (const float4*)sw1;
    const float4* w1y = (const float4*)(sw1 + HID);
    const float4* vb1 = (const float4*)sb1;
    const float4* vw2 = (const float4*)sw2;
    const float C0 = (float)(0.5 / 1025.0);
    for (uint32_t bb = 0; bb < cnt; bb += 1024) {
        uint32_t i0 = bb + tid, i1 = i0 + 256, i2 = i0 + 512, i3 = i0 + 768;
        bool v0 = i0 < cnt, v1 = i1 < cnt, v2 = i2 < cnt, v3 = i3 < cnt;
        int nA = v0 ? (int)selidx[i0] : 0;
        int nB = v1 ? (int)selidx[i1] : 0;
        int nC = v2 ? (int)selidx[i2] : 0;
        int nD = v3 ? (int)selidx[i3] : 0;
        int iA = nA / r, jA = nA % r;
        int iB = nB / r, jB = nB % r;
        int iC = nC / r, jC = nC % r;
        int iD = nD / r, jD = nD % r;
        float px0 = ((stride * (float)jA) / 1025.0f + C0) * 2.0f - 1.0f;
        float py0 = ((stride * (float)iA) / 1025.0f + C0) * 2.0f - 1.0f;
        float px1 = ((stride * (float)jB) / 1025.0f + C0) * 2.0f - 1.0f;
        float py1 = ((stride * (float)iB) / 1025.0f + C0) * 2.0f - 1.0f;
        float px2 = ((stride * (float)jC) / 1025.0f + C0) * 2.0f - 1.0f;
        float py2 = ((stride * (float)iC) / 1025.0f + C0) * 2.0f - 1.0f;
        float px3 = ((stride * (float)jD) / 1025.0f + C0) * 2.0f - 1.0f;
        float py3 = ((stride * (float)iD) / 1025.0f + C0) * 2.0f - 1.0f;
        float4 A0 = {0, 0, 0, 0}, A1 = {0, 0, 0, 0}, A2 = {0, 0, 0, 0}, A3 = {0, 0, 0, 0};
#pragma unroll 4
        for (int q = 0; q < HID / 4; ++q) {
            float4 a = w1x[q], b = w1y[q], c = vb1[q], d = vw2[q];
#define STEP(P, AX) {                                              \
            float h0 = px##P * a.x + py##P * b.x + c.x;            \
            float h1 = px##P * a.y + py##P * b.y + c.y;            \
            float h2 = px##P * a.z + py##P * b.z + c.z;            \
            float h3 = px##P * a.w + py##P * b.w + c.w;            \
            h0 = h0 > 0.f ? h0 : 0.f;                              \
            h1 = h1 > 0.f ? h1 : 0.f;                              \
            h2 = h2 > 0.f ? h2 : 0.f;                              \
            h3 = h3 > 0.f ? h3 : 0.f;                              \
            AX.x += h0 * d.x; AX.y += h1 * d.y;                    \
            AX.z += h2 * d.z; AX.w += h3 * d.w; }
            STEP(0, A0) STEP(1, A1) STEP(2, A2) STEP(3, A3)
#undef STEP
        }
#define FIN(VQ, AX, NP) if (VQ) {                                  \
        float x = ((AX.x + AX.y) + (AX.z + AX.w)) + vb2;           \
        float rr;                                                  \
        if (x >= 0.f) { rr = 1.0f / (1.0f + expf(-x)); }           \
        else { float e = expf(x); rr = e / (1.0f + e); }           \
        for (int k = 0; k < nb; ++k) occ[(size_t)k * bstride + NP] = rr; }
        FIN(v0, A0, nA) FIN(v1, A1, nB) FIN(v2, A2, nC) FIN(v3, A3, nD)
#undef FIN
    }
}

// ---------------- fallback-only broadcast (used when d_ws is too small) ----------------
__global__ __launch_bounds__(256) void k_bcast(const float* __restrict__ src, float* __restrict__ dst, int N) {
    int q = blockIdx.x * 256 + threadIdx.x;
    int n = q * 4;
    if (n + 3 < N) {
        float4 v = *(const float4*)(src + n);
#pragma unroll
        for (int k = 0; k < 8; ++k) *(float4*)(dst + (size_t)k * N + n) = v;
    } else if (n < N) {
        for (int m = n; m < N; ++m) {
            float v = src[m];
#pragma unroll
            for (int k = 0; k < 8; ++k) dst[(size_t)k * N + m] = v;
        }
    }
}

extern "C" void kernel_launch(void* const* d_in, const int* in_sizes, int n_in,
                              void* d_out, int out_size, void* d_ws, size_t ws_size,
                              hipStream_t stream) {
    const float* w1 = (const float*)d_in[0];
    const float* b1 = (const float*)d_in[1];
    const float* w2 = (const float*)d_in[2];
    const float* b2 = (const float*)d_in[3];
    float* out = (float*)d_out;

    const size_t A = (((size_t)NMAXPIX * 4) + 255) & ~(size_t)255;  // one grid buffer
    const size_t SMALL_BYTES = (size_t)4 * STAGE_U32 * 4;            // 4 stages (~338 KB)
    const size_t need = 3 * A + SMALL_BYTES;

    int fused8 = (ws_size >= need);
    char* base = fused8 ? (char*)d_ws : (char*)d_out;
    float* buf0 = (float*)(base);
    float* buf1 = (float*)(base + A);
    uint32_t* keys = (uint32_t*)(base + 2 * A);
    uint32_t* smallb = (uint32_t*)(base + 3 * A);

    // dispatch 1: zero all stage buffers (incl. flags/counters poisoned to 0xAA) + dense 65x65 eval
    k_eval0z<<<dim3(512), dim3(256), 0, stream>>>(w1, b1, w2, b2, buf0, smallb, 4 * STAGE_U32);

    const int resA[5] = {65, 129, 257, 513, 1025};
    const int nptA[5] = {0, 4096, 16384, 65536, 262144};
    float* cur = buf0;
    float* nxt = buf1;
    for (int s = 1; s < 5; ++s) {
        int rp = resA[s - 1], r = resA[s];
        int N = r * r;
        uint32_t npt = (uint32_t)nptA[s];
        uint32_t* sm = smallb + (size_t)(s - 1) * STAGE_U32;
        int nb1 = (N + 255) / 256;
        int nbu = nb1 < 1024 ? nb1 : 1024;
        int seglen = (N + NSEG - 1) / NSEG;
        float stride = 1024.0f / (float)(r - 1);

        int last = (s == 4);
        float* stage_out = (last && fused8) ? out : nxt;
        int nb = (last && fused8) ? 8 : 1;
        int bstride = (last && fused8) ? NMAXPIX : 0;

        k_upkey<<<dim3(nbu), dim3(256), 0, stream>>>(cur, rp, stage_out, r, nb, bstride, keys, sm + HA_OFF);
        k_mega<<<dim3(MBLK), dim3(256), 0, stream>>>(keys, N, seglen, npt, sm, r, stride,
                                                     stage_out, nb, bstride, w1, b1, w2, b2);
        if (!(last && fused8)) { float* tmp = cur; cur = nxt; nxt = tmp; }
    }
    if (!fused8) {
        k_bcast<<<dim3(((NMAXPIX + 3) / 4 + 255) / 256), dim3(256), 0, stream>>>(cur, out, NMAXPIX);
    }
}

// Round 11
// 257.847 us; speedup vs baseline: 1.2400x; 1.2028x over previous
//
#include <hip/hip_runtime.h>
#include <stdint.h>

#define HID 256
#define NMAXPIX (1025 * 1025)
#define NREP 4     // histogram replicas, replica-major: hist[rep*NB + bin]
#define NSEG 2048  // selection segments (one wave each; 512 blocks)
#define SELMAX 2112
#define FLAG31 0x80000000u

// per-stage small-buffer layout (u32 units)
#define HA_OFF   0        // 4 x 2048
#define HB_OFF   8192     // 4 x 2048
#define HC_OFF   16384    // 4 x 1024
#define SCAL_OFF 20480    // [0]=pfx1 [1]=rem1 [2]=pfx2 [3]=rem2 (pad 64)
#define BLKT_OFF 20544    // 512 lookback slots (tie counts | FLAG31)
#define STAGE_U32 21120

#define ALOAD32(p)  __hip_atomic_load((p), __ATOMIC_RELAXED, __HIP_MEMORY_SCOPE_AGENT)
#define ASTORE32(p, v) __hip_atomic_store((p), (v), __ATOMIC_RELAXED, __HIP_MEMORY_SCOPE_AGENT)

// ---------------- MLP eval (single point), float4 LDS weight reads ----------------
__device__ __forceinline__ float mlp_eval4(float wx, float wy,
                                           const float4* __restrict__ w1x,
                                           const float4* __restrict__ w1y,
                                           const float4* __restrict__ vb1,
                                           const float4* __restrict__ vw2, float b2v) {
    const float C0 = (float)(0.5 / 1025.0);
    float px = (wx / 1025.0f + C0) * 2.0f - 1.0f;
    float py = (wy / 1025.0f + C0) * 2.0f - 1.0f;
    float a0 = 0.f, a1 = 0.f, a2 = 0.f, a3 = 0.f;
#pragma unroll 8
    for (int q = 0; q < HID / 4; ++q) {
        float4 a = w1x[q], b = w1y[q], c = vb1[q], d = vw2[q];
        float h0 = px * a.x + py * b.x + c.x;
        float h1 = px * a.y + py * b.y + c.y;
        float h2 = px * a.z + py * b.z + c.z;
        float h3 = px * a.w + py * b.w + c.w;
        h0 = h0 > 0.f ? h0 : 0.f;
        h1 = h1 > 0.f ? h1 : 0.f;
        h2 = h2 > 0.f ? h2 : 0.f;
        h3 = h3 > 0.f ? h3 : 0.f;
        a0 += h0 * d.x;
        a1 += h1 * d.y;
        a2 += h2 * d.z;
        a3 += h3 * d.w;
    }
    float x = ((a0 + a1) + (a2 + a3)) + b2v;
    float r;
    if (x >= 0.f) { r = 1.0f / (1.0f + expf(-x)); }
    else { float e = expf(x); r = e / (1.0f + e); }
    return r;
}

// ---------------- block exclusive scan helper (256 threads) ----------------
__device__ __forceinline__ uint32_t block_exscan_256(uint32_t v, volatile uint32_t* lds4) {
    int lane = threadIdx.x & 63, w = threadIdx.x >> 6;
    uint32_t inc = v;
#pragma unroll
    for (int d = 1; d < 64; d <<= 1) {
        uint32_t o = (uint32_t)__shfl_up((int)inc, d, 64);
        if (lane >= d) inc += o;
    }
    if (lane == 63) lds4[w] = inc;
    __syncthreads();
    uint32_t woff = 0;
    for (int i = 0; i < w; ++i) woff += lds4[i];
    return woff + inc - v;
}

// ---------------- redundant per-block radix scan of a replicated histogram ----------------
// hist written by the PREVIOUS dispatch (implicit barrier -> coherent normal loads).
__device__ void scan_dev(const uint32_t* __restrict__ hist, int NB,
                         uint32_t rem_in, uint32_t prefix_in, int shift,
                         uint32_t* outp, uint32_t* outr,
                         volatile uint32_t* lds4, volatile uint32_t* ldspair) {
    int tid = threadIdx.x;
    int C = NB >> 8;                 // 8 (NB=2048) or 4 (NB=1024)
    int b0 = NB - (tid + 1) * C;     // thread 0 owns top bins
    uint32_t cnts[8];
#pragma unroll
    for (int k = 0; k < 8; ++k) cnts[k] = 0;
    for (int rep = 0; rep < NREP; ++rep) {
        const uint4* p = (const uint4*)(hist + (size_t)rep * NB + b0);
#pragma unroll
        for (int g = 0; g < 2; ++g) {
            if (g * 4 < C) {
                uint4 v = p[g];
                cnts[g * 4 + 0] += v.x;
                cnts[g * 4 + 1] += v.y;
                cnts[g * 4 + 2] += v.z;
                cnts[g * 4 + 3] += v.w;
            }
        }
    }
    uint32_t ssum = 0;
    for (int k = 0; k < C; ++k) ssum += cnts[k];
    uint32_t excl = block_exscan_256(ssum, lds4);
    uint32_t run = excl;
    for (int k = 0; k < C; ++k) {
        uint32_t c = cnts[C - 1 - k];   // descending bin order within thread
        if (rem_in > run && rem_in <= run + c) {
            ldspair[0] = (prefix_in << shift) | (uint32_t)(b0 + C - 1 - k);
            ldspair[1] = rem_in - run;
        }
        run += c;
    }
    __syncthreads();
    *outp = ldspair[0];
    *outr = ldspair[1];
}

// ---------------- eval0 + zero all per-stage buffers (replaces memset dispatch) ----------------
__global__ __launch_bounds__(256) void k_eval0z(const float* __restrict__ w1, const float* __restrict__ b1,
                                                const float* __restrict__ w2, const float* __restrict__ b2,
                                                float* __restrict__ occ, uint32_t* __restrict__ zbuf, int zcount) {
    __shared__ alignas(16) float sw1[2 * HID];
    __shared__ alignas(16) float sb1[HID];
    __shared__ alignas(16) float sw2[HID];
    int tid = threadIdx.x;
    for (int i = tid; i < 2 * HID; i += 256) sw1[i] = w1[i];
    sb1[tid] = b1[tid];
    sw2[tid] = w2[tid];
    __syncthreads();
    int gtid = blockIdx.x * 256 + tid;
    int nthreads = gridDim.x * 256;
    for (int i = gtid; i < zcount; i += nthreads) zbuf[i] = 0;
    for (int n = gtid; n < 65 * 65; n += nthreads) {
        int i = n / 65, j = n % 65;
        occ[n] = mlp_eval4(16.0f * (float)j, 16.0f * (float)i,
                           (const float4*)sw1, (const float4*)(sw1 + HID),
                           (const float4*)sb1, (const float4*)sw2, b2[0]);
    }
}

// ---------------- upsample 2x + key + msb-11 hist (grid-stride; optional 8-batch write) ----------------
__global__ __launch_bounds__(256) void k_upkey(const float* __restrict__ in, int rp,
                                               float* __restrict__ outg, int r, int nb, int bstride,
                                               uint32_t* __restrict__ keys,
                                               uint32_t* __restrict__ histA) {
    __shared__ uint32_t hist[2048];
    int tid = threadIdx.x;
    for (int k = tid; k < 2048; k += 256) hist[k] = 0;
    __syncthreads();
    int N = r * r;
    int lane = tid & 63;
    int gstride = gridDim.x * 256;
    for (int n0 = blockIdx.x * 256; n0 < N; n0 += gstride) {
        int n = n0 + tid;
        bool act = n < N;
        uint32_t key = 0;
        if (act) {
            int i = n / r, j = n % r;
            int i2 = i >> 1, j2 = j >> 1;
            float v;
            if ((i & 1) == 0) {
                if ((j & 1) == 0) {
                    v = in[i2 * rp + j2];
                } else {
                    float a = in[i2 * rp + j2], b = in[i2 * rp + j2 + 1];
                    v = a * 0.5f + b * 0.5f;
                }
            } else {
                if ((j & 1) == 0) {
                    float a = in[i2 * rp + j2], b = in[(i2 + 1) * rp + j2];
                    v = a * 0.5f + b * 0.5f;
                } else {
                    float a = in[i2 * rp + j2],      c = in[i2 * rp + j2 + 1];
                    float b = in[(i2 + 1) * rp + j2], d = in[(i2 + 1) * rp + j2 + 1];
                    float t1 = a * 0.5f + b * 0.5f;
                    float t2 = c * 0.5f + d * 0.5f;
                    v = t1 * 0.5f + t2 * 0.5f;
                }
            }
            for (int k = 0; k < nb; ++k) outg[(size_t)k * bstride + n] = v;
            float unc = -fabsf(v - 0.5f);
            uint32_t u = __float_as_uint(unc);
            key = (u & 0x80000000u) ? ~u : (u | 0x80000000u);
            keys[n] = key;
        }
        uint32_t bin = key >> 21;
        unsigned long long m = __ballot(act);
        if (m) {
            int leader = __ffsll(m) - 1;
            uint32_t lbin = (uint32_t)__shfl((int)bin, leader, 64);
            unsigned long long smk = __ballot(act && bin == lbin);
            if (smk == m) {
                if (lane == leader) atomicAdd(&hist[lbin], (uint32_t)__popcll(m));
            } else if (act) {
                atomicAdd(&hist[bin], 1u);
            }
        }
    }
    __syncthreads();
    uint32_t* myrep = histA + (size_t)(blockIdx.x & (NREP - 1)) * 2048;
    for (int k = tid; k < 2048; k += 256) {
        uint32_t c = hist[k];
        if (c) atomicAdd(&myrep[k], c);
    }
}

// ---------------- filtered histogram pass (scan of prev hist fused in, per block) ----------------
__global__ __launch_bounds__(256) void k_histmid(const uint32_t* __restrict__ keys, int N,
                                                 const uint32_t* __restrict__ prevHist,
                                                 uint32_t* __restrict__ scal,
                                                 int useNpt, uint32_t npt, int scalInIdx, int shift,
                                                 int scalOutIdx,
                                                 int fshift, int bshift, uint32_t bmask,
                                                 uint32_t* __restrict__ outHist, int NBout) {
    __shared__ uint32_t lh[2048];
    __shared__ uint32_t lds4[4];
    __shared__ uint32_t ldspair[2];
    int tid = threadIdx.x, lane = tid & 63;
    uint32_t rem_in = useNpt ? npt : scal[scalInIdx + 1];
    uint32_t pfx_in = useNpt ? 0u  : scal[scalInIdx];
    uint32_t pfx, rem;
    scan_dev(prevHist, 2048, rem_in, pfx_in, shift, &pfx, &rem, lds4, ldspair);
    if (blockIdx.x == 0 && tid == 0) { scal[scalOutIdx] = pfx; scal[scalOutIdx + 1] = rem; }
    for (int k = tid; k < 2048; k += 256) lh[k] = 0;
    __syncthreads();
    int gstride = gridDim.x * 256;
    for (int base = blockIdx.x * 256; base < N; base += gstride) {
        int n = base + tid;
        bool inb = n < N;
        uint32_t key = inb ? keys[n] : 0u;
        bool flt = inb && ((key >> fshift) == pfx);
        uint32_t bin = (key >> bshift) & bmask;
        unsigned long long m = __ballot(flt);
        if (m) {
            int leader = __ffsll(m) - 1;
            uint32_t lbin = (uint32_t)__shfl((int)bin, leader, 64);
            unsigned long long smk = __ballot(flt && bin == lbin);
            if (smk == m) {
                if (lane == leader) atomicAdd(&lh[lbin], (uint32_t)__popcll(m));
            } else if (flt) {
                atomicAdd(&lh[bin], 1u);
            }
        }
    }
    __syncthreads();
    uint32_t* myrep = outHist + (size_t)(blockIdx.x & (NREP - 1)) * NBout;
    for (int k = tid; k < NBout; k += 256) {
        uint32_t c = lh[k];
        if (c) atomicAdd(&myrep[k], c);
    }
}

// ---------------- fused: scan(histC)->K,t; tie count; decoupled lookback; select; eval ----------------
__global__ __launch_bounds__(256, 2) void k_seleval(const uint32_t* __restrict__ keys, int N, int seglen,
                                                    const uint32_t* __restrict__ histC,
                                                    const uint32_t* __restrict__ scal,
                                                    uint32_t* __restrict__ blkT,
                                                    int r, float stride,
                                                    float* __restrict__ occ, int nb, int bstride,
                                                    const float* __restrict__ w1, const float* __restrict__ b1,
                                                    const float* __restrict__ w2, const float* __restrict__ b2) {
    __shared__ alignas(16) float sw1[2 * HID];
    __shared__ alignas(16) float sb1[HID];
    __shared__ alignas(16) float sw2[HID];
    __shared__ uint32_t lds4[4];
    __shared__ uint32_t ldspair[2];
    __shared__ uint32_t wcnt[4];
    __shared__ uint32_t bp_s;
    __shared__ uint32_t selcnt;
    __shared__ uint32_t selidx[SELMAX];
    int tid = threadIdx.x, lane = tid & 63, w = tid >> 6;
    int blk = blockIdx.x;
    for (int i = tid; i < 2 * HID; i += 256) sw1[i] = w1[i];
    sb1[tid] = b1[tid];
    sw2[tid] = w2[tid];
    if (tid == 0) selcnt = 0;
    __syncthreads();

    // K,t: redundant per-block scan of histC (written by previous dispatch -> coherent)
    uint32_t K, t;
    scan_dev(histC, 1024, scal[3], scal[2], 10, &K, &t, lds4, ldspair);

    // per-wave tie count of own segment
    int wv = blk * 4 + w;
    int s0 = wv * seglen;
    int s1 = s0 + seglen; if (s1 > N) s1 = N;
    {
        uint32_t tcnt = 0;
        for (int base = s0; base < s1; base += 64) {
            int n = base + lane;
            if (n < s1) tcnt += (keys[n] == K) ? 1u : 0u;
        }
#pragma unroll
        for (int d = 32; d; d >>= 1) tcnt += (uint32_t)__shfl_down((int)tcnt, d, 64);
        if (lane == 0) wcnt[w] = tcnt;
    }
    __syncthreads();
    // decoupled lookback (wave 0 only): publish own block count BEFORE spinning on lower blocks
    if (w == 0) {
        if (lane == 0) {
            uint32_t tot = wcnt[0] + wcnt[1] + wcnt[2] + wcnt[3];
            ASTORE32(&blkT[blk], tot | FLAG31);
        }
        uint32_t bp = 0;
        for (int i = lane; i < blk; i += 64) {
            uint32_t v;
            for (;;) {
                v = ALOAD32(&blkT[i]);
                if (v & FLAG31) break;
                __builtin_amdgcn_s_sleep(2);
            }
            bp += v & 0x7FFFFFFFu;
        }
#pragma unroll
        for (int d = 32; d; d >>= 1) bp += (uint32_t)__shfl_down((int)bp, d, 64);
        if (lane == 0) bp_s = bp;
    }
    __syncthreads();
    uint32_t tp = bp_s;
    for (int ww = 0; ww < w; ++ww) tp += wcnt[ww];

    // select (exact top-k, index-ascending ties) -> LDS compaction
    uint32_t tie_run = tp;
    unsigned long long lowmask = (lane == 63) ? ~0ull >> 1 : ((1ull << lane) - 1ull);
    for (int base = s0; base < s1; base += 64) {
        int n = base + lane;
        bool inb = n < s1;
        uint32_t key = inb ? keys[n] : 0u;
        bool gt = inb && (key > K);
        bool tie = inb && (key == K);
        unsigned long long tm = __ballot(tie);
        uint32_t trank = tie_run + (uint32_t)__popcll(tm & lowmask);
        bool sel = gt || (tie && trank < t);
        unsigned long long smk = __ballot(sel);
        if (smk) {
            int leader = __ffsll(smk) - 1;
            uint32_t wbase = 0;
            if (lane == leader) wbase = atomicAdd(&selcnt, (uint32_t)__popcll(smk));
            wbase = (uint32_t)__shfl((int)wbase, leader, 64);
            if (sel) selidx[wbase + (uint32_t)__popcll(smk & lowmask)] = (uint32_t)n;
        }
        tie_run += (uint32_t)__popcll(tm);
    }
    __syncthreads();

    // dense eval: 4 points per thread per weight sweep
    uint32_t cnt = selcnt;
    float vb2 = b2[0];
    const float4* w1x = (const float4*)sw1;
    const float4* w1y = (const float4*)(sw1 + HID);
    const float4* vb1 = (const float4*)sb1;
    const float4* vw2 = (const float4*)sw2;
    const float C0 = (float)(0.5 / 1025.0);
    for (uint32_t bb = 0; bb < cnt; bb += 1024) {
        uint32_t i0 = bb + tid, i1 = i0 + 256, i2 = i0 + 512, i3 = i0 + 768;
        bool v0 = i0 < cnt, v1 = i1 < cnt, v2 = i2 < cnt, v3 = i3 < cnt;
        int nA = v0 ? (int)selidx[i0] : 0;
        int nB = v1 ? (int)selidx[i1] : 0;
        int nC = v2 ? (int)selidx[i2] : 0;
        int nD = v3 ? (int)selidx[i3] : 0;
        int iA = nA / r, jA = nA % r;
        int iB = nB / r, jB = nB % r;
        int iC = nC / r, jC = nC % r;
        int iD = nD / r, jD = nD % r;
        float px0 = ((stride * (float)jA) / 1025.0f + C0) * 2.0f - 1.0f;
        float py0 = ((stride * (float)iA) / 1025.0f + C0) * 2.0f - 1.0f;
        float px1 = ((stride * (float)jB) / 1025.0f + C0) * 2.0f - 1.0f;
        float py1 = ((stride * (float)iB) / 1025.0f + C0) * 2.0f - 1.0f;
        float px2 = ((stride * (float)jC) / 1025.0f + C0) * 2.0f - 1.0f;
        float py2 = ((stride * (float)iC) / 1025.0f + C0) * 2.0f - 1.0f;
        float px3 = ((stride * (float)jD) / 1025.0f + C0) * 2.0f - 1.0f;
        float py3 = ((stride * (float)iD) / 1025.0f + C0) * 2.0f - 1.0f;
        float4 A0 = {0, 0, 0, 0}, A1 = {0, 0, 0, 0}, A2 = {0, 0, 0, 0}, A3 = {0, 0, 0, 0};
#pragma unroll 4
        for (int q = 0; q < HID / 4; ++q) {
            float4 a = w1x[q], b = w1y[q], c = vb1[q], d = vw2[q];
#define STEP(P, AX) {                                              \
            float h0 = px##P * a.x + py##P * b.x + c.x;            \
            float h1 = px##P * a.y + py##P * b.y + c.y;            \
            float h2 = px##P * a.z + py##P * b.z + c.z;            \
            float h3 = px##P * a.w + py##P * b.w + c.w;            \
            h0 = h0 > 0.f ? h0 : 0.f;                              \
            h1 = h1 > 0.f ? h1 : 0.f;                              \
            h2 = h2 > 0.f ? h2 : 0.f;                              \
            h3 = h3 > 0.f ? h3 : 0.f;                              \
            AX.x += h0 * d.x; AX.y += h1 * d.y;                    \
            AX.z += h2 * d.z; AX.w += h3 * d.w; }
            STEP(0, A0) STEP(1, A1) STEP(2, A2) STEP(3, A3)
#undef STEP
        }
#define FIN(VQ, AX, NP) if (VQ) {                                  \
        float x = ((AX.x + AX.y) + (AX.z + AX.w)) + vb2;           \
        float rr;                                                  \
        if (x >= 0.f) { rr = 1.0f / (1.0f + expf(-x)); }           \
        else { float e = expf(x); rr = e / (1.0f + e); }           \
        for (int k = 0; k < nb; ++k) occ[(size_t)k * bstride + NP] = rr; }
        FIN(v0, A0, nA) FIN(v1, A1, nB) FIN(v2, A2, nC) FIN(v3, A3, nD)
#undef FIN
    }
}

// ---------------- fallback-only broadcast (used when d_ws is too small) ----------------
__global__ __launch_bounds__(256) void k_bcast(const float* __restrict__ src, float* __restrict__ dst, int N) {
    int q = blockIdx.x * 256 + threadIdx.x;
    int n = q * 4;
    if (n + 3 < N) {
        float4 v = *(const float4*)(src + n);
#pragma unroll
        for (int k = 0; k < 8; ++k) *(float4*)(dst + (size_t)k * N + n) = v;
    } else if (n < N) {
        for (int m = n; m < N; ++m) {
            float v = src[m];
#pragma unroll
            for (int k = 0; k < 8; ++k) dst[(size_t)k * N + m] = v;
        }
    }
}

extern "C" void kernel_launch(void* const* d_in, const int* in_sizes, int n_in,
                              void* d_out, int out_size, void* d_ws, size_t ws_size,
                              hipStream_t stream) {
    const float* w1 = (const float*)d_in[0];
    const float* b1 = (const float*)d_in[1];
    const float* w2 = (const float*)d_in[2];
    const float* b2 = (const float*)d_in[3];
    float* out = (float*)d_out;

    const size_t A = (((size_t)NMAXPIX * 4) + 255) & ~(size_t)255;  // one grid buffer
    const size_t SMALL_BYTES = (size_t)4 * STAGE_U32 * 4;            // 4 stages (~338 KB)
    const size_t need = 3 * A + SMALL_BYTES;

    int fused8 = (ws_size >= need);  // stage-4 writes all 8 batches directly when ws holds scratch
    char* base = fused8 ? (char*)d_ws : (char*)d_out;
    float* buf0 = (float*)(base);
    float* buf1 = (float*)(base + A);
    uint32_t* keys = (uint32_t*)(base + 2 * A);
    uint32_t* smallb = (uint32_t*)(base + 3 * A);

    // dispatch 1: zero all stage buffers (hists + blkT flags) + dense 65x65 eval
    k_eval0z<<<dim3(512), dim3(256), 0, stream>>>(w1, b1, w2, b2, buf0, smallb, 4 * STAGE_U32);

    const int resA[5] = {65, 129, 257, 513, 1025};
    const int nptA[5] = {0, 4096, 16384, 65536, 262144};
    float* cur = buf0;
    float* nxt = buf1;
    for (int s = 1; s < 5; ++s) {
        int rp = resA[s - 1], r = resA[s];
        int N = r * r;
        uint32_t npt = (uint32_t)nptA[s];
        uint32_t* sm = smallb + (size_t)(s - 1) * STAGE_U32;
        uint32_t* histA = sm + HA_OFF;
        uint32_t* histB = sm + HB_OFF;
        uint32_t* histC = sm + HC_OFF;
        uint32_t* scal  = sm + SCAL_OFF;
        uint32_t* blkT  = sm + BLKT_OFF;
        int nb1 = (N + 255) / 256;
        int nbu = nb1 < 1024 ? nb1 : 1024;
        int seglen = (N + NSEG - 1) / NSEG;
        float stride = 1024.0f / (float)(r - 1);

        int last = (s == 4);
        float* stage_out = (last && fused8) ? out : nxt;
        int nb = (last && fused8) ? 8 : 1;
        int bstride = (last && fused8) ? NMAXPIX : 0;

        k_upkey<<<dim3(nbu), dim3(256), 0, stream>>>(cur, rp, stage_out, r, nb, bstride, keys, histA);
        k_histmid<<<dim3(512), dim3(256), 0, stream>>>(keys, N, histA, scal, 1, npt, 0, 0,
                                                       0, 21, 10, 0x7FFu, histB, 2048);
        k_histmid<<<dim3(512), dim3(256), 0, stream>>>(keys, N, histB, scal, 0, 0u, 0, 11,
                                                       2, 10, 0, 0x3FFu, histC, 1024);
        k_seleval<<<dim3(NSEG / 4), dim3(256), 0, stream>>>(keys, N, seglen, histC, scal, blkT,
                                                            r, stride, stage_out, nb, bstride,
                                                            w1, b1, w2, b2);
        if (!(last && fused8)) { float* tmp = cur; cur = nxt; nxt = tmp; }
    }
    if (!fused8) {
        k_bcast<<<dim3(((NMAXPIX + 3) / 4 + 255) / 256), dim3(256), 0, stream>>>(cur, out, NMAXPIX);
    }
}